// Round 7
// baseline (548.826 us; speedup 1.0000x reference)
//
#include <hip/hip_runtime.h>
#include <stdint.h>

typedef __attribute__((ext_vector_type(8))) short short8;
typedef __attribute__((ext_vector_type(4))) float f32x4;
typedef __attribute__((ext_vector_type(16))) float f32x16;
typedef __attribute__((ext_vector_type(4))) unsigned int uint4v;

__device__ __forceinline__ short cvt_bf16(float f) {
  uint32_t u = __builtin_bit_cast(uint32_t, f);
  u += 0x7FFFu + ((u >> 16) & 1u);   // RNE
  return (short)(u >> 16);
}

__device__ __forceinline__ float bf16_to_f32(short s) {
  return __builtin_bit_cast(float, (uint32_t)((unsigned short)s) << 16);
}

__device__ __forceinline__ void gload_lds16(const void* g, void* l) {
  __builtin_amdgcn_global_load_lds(
      (const __attribute__((address_space(1))) void*)g,
      (__attribute__((address_space(3))) void*)l, 16, 0, 0);
}

// ---------------- weight transpose: src fp32 [512][512] -> dst bf16 [n][c] ----------------
__global__ __launch_bounds__(256) void k_transpose_w(const float* __restrict__ src,
                                                     short* __restrict__ dst) {
  __shared__ float t[32][33];
  int n0 = blockIdx.x * 32, c0 = blockIdx.y * 32;
  int lx = threadIdx.x & 31, ly = threadIdx.x >> 5;
#pragma unroll
  for (int i = 0; i < 4; ++i) {
    int c = ly + i * 8;
    t[c][lx] = src[(size_t)(c0 + c) * 512 + n0 + lx];
  }
  __syncthreads();
#pragma unroll
  for (int i = 0; i < 4; ++i) {
    int n = ly + i * 8;
    dst[(size_t)(n0 + n) * 512 + c0 + lx] = cvt_bf16(t[lx][n]);
  }
}

__global__ void k_bias_concat(const float* __restrict__ bq, const float* __restrict__ bk,
                              float* __restrict__ bqk) {
  int i = blockIdx.x * 256 + threadIdx.x;
  if (i < 512) bqk[i] = bq[i];
  else if (i < 1024) bqk[i] = bk[i - 512];
}

// ---------------- GroupNorm stats ----------------
__global__ __launch_bounds__(256) void k_gn_stats(const float* __restrict__ x,
                                                  float* __restrict__ stats) {
  int bg = blockIdx.x;
  const float* p = x + (size_t)bg * 65536;
  float s = 0.f, ss = 0.f;
#pragma unroll 4
  for (int i = 0; i < 64; ++i) {
    float4 v = *(const float4*)(p + i * 1024 + threadIdx.x * 4);
    s += v.x + v.y + v.z + v.w;
    ss += v.x * v.x + v.y * v.y + v.z * v.z + v.w * v.w;
  }
#pragma unroll
  for (int m = 1; m < 64; m <<= 1) {
    s += __shfl_xor(s, m, 64);
    ss += __shfl_xor(ss, m, 64);
  }
  __shared__ float red[8];
  int w = threadIdx.x >> 6;
  if ((threadIdx.x & 63) == 0) { red[w * 2] = s; red[w * 2 + 1] = ss; }
  __syncthreads();
  if (threadIdx.x == 0) {
    float S1 = red[0] + red[2] + red[4] + red[6];
    float S2 = red[1] + red[3] + red[5] + red[7];
    float mean = S1 * (1.f / 65536.f);
    float var = S2 * (1.f / 65536.f) - mean * mean;
    stats[bg * 2] = mean;
    stats[bg * 2 + 1] = rsqrtf(var + 1e-6f);
  }
}

// ---------------- normalize + transpose -> h_t[b*4096+p][c] bf16 ----------------
__global__ __launch_bounds__(256) void k_gn_apply(const float* __restrict__ x,
    const float* __restrict__ stats, const float* __restrict__ gsc,
    const float* __restrict__ gbi, short* __restrict__ h_t) {
  __shared__ float t[64][65];
  int p0 = blockIdx.x * 64, c0 = blockIdx.y * 64, b = blockIdx.z;
  int lp = threadIdx.x & 63, lc = threadIdx.x >> 6;
#pragma unroll
  for (int i = 0; i < 16; ++i) {
    int c = c0 + lc * 16 + i;
    float mean = stats[(b * 32 + (c >> 4)) * 2];
    float rstd = stats[(b * 32 + (c >> 4)) * 2 + 1];
    float v = x[((size_t)b * 512 + c) * 4096 + p0 + lp];
    t[lc * 16 + i][lp] = (v - mean) * rstd * gsc[c] + gbi[c];
  }
  __syncthreads();
  int pl = threadIdx.x >> 2;
  int cs = (threadIdx.x & 3) * 16;
  short8 v8a, v8b;
#pragma unroll
  for (int j = 0; j < 8; ++j) v8a[j] = cvt_bf16(t[cs + j][pl]);
#pragma unroll
  for (int j = 0; j < 8; ++j) v8b[j] = cvt_bf16(t[cs + 8 + j][pl]);
  size_t o = ((size_t)(b * 4096 + p0 + pl)) * 512 + c0 + cs;
  *(short8*)(h_t + o) = v8a;
  *(short8*)(h_t + o + 8) = v8b;
}

// ---------------- GEMM: A[M][512] x B[N][512] (K-major bf16) -> C[M][N] ----------------
template <int BIAS_M, int FINAL>
__global__ __launch_bounds__(256) void k_gemm(const short* __restrict__ A,
    const short* __restrict__ Bm, const float* __restrict__ bias,
    short* __restrict__ Cb, float* __restrict__ Cf, const float* __restrict__ resid,
    int ldc) {
  __shared__ __align__(16) short a_lds[128 * 32];
  __shared__ __align__(16) short b_lds[128 * 32];
  int m0 = blockIdx.x * 128, n0 = blockIdx.y * 128;
  int lane = threadIdx.x & 63, wid = threadIdx.x >> 6;
  int h16 = lane >> 4, l16 = lane & 15;
  int wr = wid >> 1, wc = wid & 1;

  f32x4 acc[4][4];
#pragma unroll
  for (int mi = 0; mi < 4; ++mi)
#pragma unroll
    for (int ni = 0; ni < 4; ++ni) acc[mi][ni] = (f32x4){0.f, 0.f, 0.f, 0.f};

  for (int kk = 0; kk < 16; ++kk) {
#pragma unroll
    for (int i = 0; i < 4; ++i) {
      int idx = wid * 4 + i;
      int mat = idx >> 3, h = (idx >> 1) & 3, rh = idx & 1;
      const short* src = (mat ? Bm : A) +
          ((size_t)((mat ? n0 : m0) + rh * 64 + lane)) * 512 + kk * 32 + h * 8;
      short* dst = (mat ? b_lds : a_lds) + (h * 128 + rh * 64) * 8;
      gload_lds16(src, dst);
    }
    asm volatile("s_waitcnt vmcnt(0)" ::: "memory");
    __syncthreads();
    short8 af[4], bf[4];
#pragma unroll
    for (int mi = 0; mi < 4; ++mi)
      af[mi] = *(const short8*)(a_lds + (h16 * 128 + wr * 64 + mi * 16 + l16) * 8);
#pragma unroll
    for (int ni = 0; ni < 4; ++ni)
      bf[ni] = *(const short8*)(b_lds + (h16 * 128 + wc * 64 + ni * 16 + l16) * 8);
#pragma unroll
    for (int mi = 0; mi < 4; ++mi)
#pragma unroll
      for (int ni = 0; ni < 4; ++ni)
        acc[mi][ni] = __builtin_amdgcn_mfma_f32_16x16x32_bf16(af[mi], bf[ni], acc[mi][ni], 0, 0, 0);
    __syncthreads();
  }

#pragma unroll
  for (int mi = 0; mi < 4; ++mi)
#pragma unroll
    for (int ni = 0; ni < 4; ++ni)
#pragma unroll
      for (int r = 0; r < 4; ++r) {
        int row = m0 + wr * 64 + mi * 16 + 4 * h16 + r;
        int col = n0 + wc * 64 + ni * 16 + l16;
        float v = acc[mi][ni][r] + (BIAS_M ? bias[row] : bias[col]);
        if (FINAL) {
          size_t oidx = ((size_t)((col >> 12) * 512 + row)) * 4096 + (col & 4095);
          Cf[oidx] = v + resid[oidx];
        } else {
          Cb[(size_t)row * ldc + col] = cvt_bf16(v);
        }
      }
}

// ---------------- flash attention v7: 2 independent blocks per CU ----------------
// QBLK=64, KVBLK=32, kv-split=2, 4 waves = 2 qg x 2 dh, 32x32x16 MFMA.
// LDS = K32 + V32 + Sx16 = 80KB -> exactly 2 blocks/CU (independent streams per
// SIMD fill each other's bubbles). Wait/barrier structure = v3's verified
// single-buffer schedule. QK^T accumulator split into 2 chains.
__global__ __launch_bounds__(256, 2) void k_flash7(const short* __restrict__ qk,
    const short* __restrict__ v_t, short* __restrict__ oa, short* __restrict__ ob,
    float* __restrict__ ml) {
  __shared__ __align__(16) short k_lds[32 * 512];   // [ks(32)][lane(64)][j(8)] 32KB
  __shared__ __align__(16) short v_lds[32 * 512];   // [si(32)][lane(64)][j(8)] 32KB
  __shared__ __align__(16) float s_lds[4 * 1024];   // [wid][q4(4)][lane(64)][4] 16KB

  const int tid = threadIdx.x;
  const int lane = tid & 63, wid = tid >> 6;        // wid 0..3
  const int qg = wid >> 1, dh = wid & 1;
  const int l31 = lane & 31, h = lane >> 5;
  const int bx = blockIdx.x;
  const int combo = bx & 7, qt = bx >> 3;           // qt 0..63
  const int b = combo >> 1, s = combo & 1;
  const float K2 = 0.06376649f;  // log2(e)/sqrt(512)

  // Q B-frags: col=q(l31), k-elems d = dh*256 + s_*16 + h*8 + j
  short8 qf[16];
  {
    const short* qbase = qk + ((size_t)(b * 4096 + qt * 64 + qg * 32 + l31)) * 1024
                         + dh * 256 + h * 8;
#pragma unroll
    for (int s_ = 0; s_ < 16; ++s_) qf[s_] = *(const short8*)(qbase + s_ * 16);
  }

  const size_t kvrow0 = (size_t)(b * 4096 + s * 2048);

#define STAGE_K7(T)                                                                   \
  {                                                                                   \
    int t_ = (T);                                                                     \
    _Pragma("unroll") for (int i = 0; i < 8; ++i) {                                   \
      int ks = wid * 8 + i;                                                           \
      gload_lds16(qk + (kvrow0 + t_ * 32 + l31) * 1024 + 512 + ks * 16 + h * 8,       \
                  k_lds + ks * 512);                                                  \
    }                                                                                 \
  }
#define STAGE_V7(T)                                                                   \
  {                                                                                   \
    int t_ = (T);                                                                     \
    _Pragma("unroll") for (int i = 0; i < 8; ++i) {                                   \
      int si = wid * 8 + i;                                                           \
      int ks = si >> 4, d0 = si & 15;                                                 \
      gload_lds16(v_t + (size_t)(d0 * 32 + l31) * 16384                               \
                      + (kvrow0 + t_ * 32 + ks * 16 + h * 8),                         \
                  v_lds + si * 512);                                                  \
    }                                                                                 \
  }

  STAGE_K7(0);
  STAGE_V7(0);
  asm volatile("s_waitcnt vmcnt(0)" ::: "memory");
  __builtin_amdgcn_s_barrier();
  __builtin_amdgcn_sched_barrier(0);

  float m_run = -3.0e38f, l_run = 0.f;
  f32x16 acc[8];
#pragma unroll
  for (int tl = 0; tl < 8; ++tl)
#pragma unroll
    for (int r = 0; r < 16; ++r) acc[tl][r] = 0.f;

  for (int t = 0; t < 64; ++t) {
    const int tn = (t + 1 < 64) ? t + 1 : 63;
    // ---- QK^T partial over dh's 256 d: S^T [32 kv][32 q]; 2 parallel 8-chains
    f32x16 stA, stB;
#pragma unroll
    for (int r = 0; r < 16; ++r) { stA[r] = 0.f; stB[r] = 0.f; }
    __builtin_amdgcn_s_setprio(1);
#pragma unroll
    for (int s_ = 0; s_ < 8; ++s_) {
      short8 kfA = *(const short8*)(k_lds + ((dh * 16 + s_) * 64 + lane) * 8);
      short8 kfB = *(const short8*)(k_lds + ((dh * 16 + 8 + s_) * 64 + lane) * 8);
      stA = __builtin_amdgcn_mfma_f32_32x32x16_bf16(kfA, qf[s_], stA, 0, 0, 0);
      stB = __builtin_amdgcn_mfma_f32_32x32x16_bf16(kfB, qf[8 + s_], stB, 0, 0, 0);
    }
    __builtin_amdgcn_s_setprio(0);
    f32x16 st;
#pragma unroll
    for (int r = 0; r < 16; ++r) st[r] = stA[r] + stB[r];
    // write own partial to s_lds[wid]
    {
      float* sp = s_lds + wid * 1024 + lane * 4;
#pragma unroll
      for (int q4 = 0; q4 < 4; ++q4) {
        f32x4 v = {st[q4 * 4 + 0], st[q4 * 4 + 1], st[q4 * 4 + 2], st[q4 * 4 + 3]};
        *(f32x4*)(sp + q4 * 256) = v;
      }
    }
    // V(t) landed; S writes visible
    asm volatile("s_waitcnt vmcnt(0) lgkmcnt(0)" ::: "memory");
    __builtin_amdgcn_s_barrier();                                // BarA
    __builtin_amdgcn_sched_barrier(0);
    STAGE_K7(tn);   // k_lds overwrite (QK reads drained before BarA)
    // combine with partner (dh^1)
    {
      const float* sp = s_lds + (wid ^ 1) * 1024 + lane * 4;
#pragma unroll
      for (int q4 = 0; q4 < 4; ++q4) {
        f32x4 v = *(const f32x4*)(sp + q4 * 256);
        st[q4 * 4 + 0] += v[0]; st[q4 * 4 + 1] += v[1];
        st[q4 * 4 + 2] += v[2]; st[q4 * 4 + 3] += v[3];
      }
    }
    // ---- softmax, per q-col (= per lane); tree max + shfl_xor cross-half
    float u0 = fmaxf(st[0], st[1]),  u1 = fmaxf(st[2], st[3]);
    float u2 = fmaxf(st[4], st[5]),  u3 = fmaxf(st[6], st[7]);
    float u4 = fmaxf(st[8], st[9]),  u5 = fmaxf(st[10], st[11]);
    float u6 = fmaxf(st[12], st[13]), u7 = fmaxf(st[14], st[15]);
    float mt = fmaxf(fmaxf(fmaxf(u0, u1), fmaxf(u2, u3)),
                     fmaxf(fmaxf(u4, u5), fmaxf(u6, u7)));
    mt = fmaxf(mt, __shfl_xor(mt, 32));
    if (__any(mt > m_run + 45.0f)) {
      float mnew = fmaxf(m_run, mt);
      float rs = exp2f((m_run - mnew) * K2);
      m_run = mnew;
      l_run *= rs;
#pragma unroll
      for (int r = 0; r < 16; ++r) {
        int rowq = (r & 3) + 8 * (r >> 2) + 4 * h;
        float rr = __shfl(rs, rowq);
#pragma unroll
        for (int tl = 0; tl < 8; ++tl) acc[tl][r] *= rr;
      }
    }
    float ls = 0.f;
#pragma unroll
    for (int r = 0; r < 16; ++r) { st[r] = exp2f((st[r] - m_run) * K2); ls += st[r]; }
    ls += __shfl_xor(ls, 32);
    l_run += ls;
    // ---- P pack (in-reg) + PV
    __builtin_amdgcn_s_setprio(1);
#pragma unroll
    for (int ks = 0; ks < 2; ++ks) {
      unsigned int a0, a1, a2, a3;
      int bse = ks * 8;
      asm("v_cvt_pk_bf16_f32 %0, %1, %2" : "=v"(a0) : "v"(st[bse + 0]), "v"(st[bse + 1]));
      asm("v_cvt_pk_bf16_f32 %0, %1, %2" : "=v"(a1) : "v"(st[bse + 2]), "v"(st[bse + 3]));
      asm("v_cvt_pk_bf16_f32 %0, %1, %2" : "=v"(a2) : "v"(st[bse + 4]), "v"(st[bse + 5]));
      asm("v_cvt_pk_bf16_f32 %0, %1, %2" : "=v"(a3) : "v"(st[bse + 6]), "v"(st[bse + 7]));
      asm("v_permlane32_swap_b32 %0, %1" : "+v"(a0), "+v"(a2));
      asm("v_permlane32_swap_b32 %0, %1" : "+v"(a1), "+v"(a3));
      uint4v w; w[0] = a0; w[1] = a1; w[2] = a2; w[3] = a3;
      short8 pa = __builtin_bit_cast(short8, w);
#pragma unroll
      for (int tl = 0; tl < 8; ++tl) {
        short8 vb = *(const short8*)(v_lds + ((ks * 16 + dh * 8 + tl) * 64 + lane) * 8);
        acc[tl] = __builtin_amdgcn_mfma_f32_32x32x16_bf16(pa, vb, acc[tl], 0, 0, 0);
      }
    }
    __builtin_amdgcn_s_setprio(0);
    // K(t+1) landed; PV + exchange LDS reads done
    asm volatile("s_waitcnt vmcnt(0) lgkmcnt(0)" ::: "memory");
    __builtin_amdgcn_s_barrier();                                // BarB
    __builtin_amdgcn_sched_barrier(0);
    STAGE_V7(tn);   // v_lds overwrite (PV reads drained at BarB)
  }

  // epilogue: normalized bf16 partial + (m, l)
  float linv = 1.0f / l_run;
  short* obuf = (s == 0) ? oa : ob;
#pragma unroll
  for (int r = 0; r < 16; ++r) {
    int rowq = (r & 3) + 8 * (r >> 2) + 4 * h;
    float li = __shfl(linv, rowq);
    size_t grow = ((size_t)(b * 4096 + qt * 64 + qg * 32 + rowq)) * 512;
#pragma unroll
    for (int tl = 0; tl < 8; ++tl)
      obuf[grow + dh * 256 + tl * 32 + l31] = cvt_bf16(acc[tl][r] * li);
  }
  if (dh == 0 && lane < 32) {
    int gq = b * 4096 + qt * 64 + qg * 32 + lane;
    ml[((size_t)s * 16384 + gq) * 2 + 0] = m_run;
    ml[((size_t)s * 16384 + gq) * 2 + 1] = l_run;
  }
#undef STAGE_K7
#undef STAGE_V7
}

// ---------------- combine the two kv-split partials (in place over Ob) ----------------
__global__ __launch_bounds__(256) void k_combine(const short* __restrict__ oa,
    const float* __restrict__ ml, short* __restrict__ ob_out) {
  int gq = blockIdx.x * 4 + (threadIdx.x >> 6);
  int d0 = (threadIdx.x & 63) * 8;
  const float K2 = 0.06376649f;
  float ma = ml[(size_t)gq * 2 + 0], la = ml[(size_t)gq * 2 + 1];
  float mb = ml[((size_t)16384 + gq) * 2 + 0], lb = ml[((size_t)16384 + gq) * 2 + 1];
  float m = fmaxf(ma, mb);
  float wa = exp2f((ma - m) * K2) * la;
  float wb = exp2f((mb - m) * K2) * lb;
  float denom = wa + wb;
  float fa, fb;
  if (isfinite(denom) && denom > 0.f) {
    float inv = 1.f / denom;
    fa = wa * inv; fb = wb * inv;
  } else {
    fa = (ma >= mb) ? 1.f : 0.f;
    fb = 1.f - fa;
  }
  short8 a = *(const short8*)(oa + (size_t)gq * 512 + d0);
  short8 bv = *(const short8*)(ob_out + (size_t)gq * 512 + d0);
  short8 o;
#pragma unroll
  for (int j = 0; j < 8; ++j)
    o[j] = cvt_bf16(fa * bf16_to_f32(a[j]) + fb * bf16_to_f32(bv[j]));
  *(short8*)(ob_out + (size_t)gq * 512 + d0) = o;
}

extern "C" void kernel_launch(void* const* d_in, const int* in_sizes, int n_in,
                              void* d_out, int out_size, void* d_ws, size_t ws_size,
                              hipStream_t stream) {
  const float* x   = (const float*)d_in[0];
  const float* gsc = (const float*)d_in[1];
  const float* gbi = (const float*)d_in[2];
  const float* wq  = (const float*)d_in[3];
  const float* bq  = (const float*)d_in[4];
  const float* wk  = (const float*)d_in[5];
  const float* bk  = (const float*)d_in[6];
  const float* wv  = (const float*)d_in[7];
  const float* bv  = (const float*)d_in[8];
  const float* wo  = (const float*)d_in[9];
  const float* bo  = (const float*)d_in[10];
  float* out = (float*)d_out;

  char* ws = (char*)d_ws;
  float* stats = (float*)ws;                             // 1 KB
  float* bqk   = (float*)(ws + 4096);                    // 4 KB
  short* wqk_t = (short*)(ws + 16384);                   // 1 MB  [1024][512]
  short* wv_t  = (short*)(ws + 16384 + (1u << 20));      // 0.5 MB
  short* wo_t  = (short*)(ws + 16384 + (1u << 20) + (1u << 19));
  char*  big   = ws + 16384 + (1u << 21);
  short* h_t   = (short*)big;                            // 16 MB [16384][512]; reused as Oa
  short* qkb   = (short*)(big + (16ll << 20));           // 32 MB [16384][1024]
  short* v_t   = (short*)(big + (48ll << 20));           // 16 MB [512][16384]
  short* o_at  = (short*)(big + (64ll << 20));           // 16 MB [16384][512]; Ob then final
  float* mlbuf = (float*)(big + (80ll << 20));           // 256 KB [2][16384][2]

  dim3 b256(256);
  k_transpose_w<<<dim3(16, 16), b256, 0, stream>>>(wq, wqk_t);
  k_transpose_w<<<dim3(16, 16), b256, 0, stream>>>(wk, wqk_t + 512 * 512);
  k_transpose_w<<<dim3(16, 16), b256, 0, stream>>>(wv, wv_t);
  k_transpose_w<<<dim3(16, 16), b256, 0, stream>>>(wo, wo_t);
  k_bias_concat<<<4, 256, 0, stream>>>(bq, bk, bqk);
  k_gn_stats<<<128, b256, 0, stream>>>(x, stats);
  k_gn_apply<<<dim3(64, 8, 4), b256, 0, stream>>>(x, stats, gsc, gbi, h_t);
  // Q|K projection -> qkb[16384][1024]
  k_gemm<0, 0><<<dim3(128, 8), b256, 0, stream>>>(h_t, wqk_t, bqk, qkb, nullptr, nullptr, 1024);
  // V projection transposed -> v_t[512][16384]
  k_gemm<1, 0><<<dim3(4, 128), b256, 0, stream>>>(wv_t, h_t, bv, v_t, nullptr, nullptr, 16384);
  // flash attention (h_t now dead -> Oa; o_at holds Ob)
  k_flash7<<<dim3(512), b256, 0, stream>>>(qkb, v_t, h_t, o_at, mlbuf);
  k_combine<<<dim3(4096), b256, 0, stream>>>(h_t, mlbuf, o_at);
  // output projection transposed + bias + residual -> fp32 out
  k_gemm<1, 1><<<dim3(4, 128), b256, 0, stream>>>(wo_t, o_at, bo, nullptr, out, x, 0);
}

// Round 8
// 379.206 us; speedup vs baseline: 1.4473x; 1.4473x over previous
//
#include <hip/hip_runtime.h>
#include <stdint.h>

typedef __attribute__((ext_vector_type(8))) short short8;
typedef __attribute__((ext_vector_type(4))) float f32x4;
typedef __attribute__((ext_vector_type(16))) float f32x16;
typedef __attribute__((ext_vector_type(4))) unsigned int uint4v;

__device__ __forceinline__ short cvt_bf16(float f) {
  uint32_t u = __builtin_bit_cast(uint32_t, f);
  u += 0x7FFFu + ((u >> 16) & 1u);   // RNE
  return (short)(u >> 16);
}

__device__ __forceinline__ float bf16_to_f32(short s) {
  return __builtin_bit_cast(float, (uint32_t)((unsigned short)s) << 16);
}

__device__ __forceinline__ void gload_lds16(const void* g, void* l) {
  __builtin_amdgcn_global_load_lds(
      (const __attribute__((address_space(1))) void*)g,
      (__attribute__((address_space(3))) void*)l, 16, 0, 0);
}

// ---------------- weight transpose: src fp32 [512][512] -> dst bf16 [n][c] ----------------
__global__ __launch_bounds__(256) void k_transpose_w(const float* __restrict__ src,
                                                     short* __restrict__ dst) {
  __shared__ float t[32][33];
  int n0 = blockIdx.x * 32, c0 = blockIdx.y * 32;
  int lx = threadIdx.x & 31, ly = threadIdx.x >> 5;
#pragma unroll
  for (int i = 0; i < 4; ++i) {
    int c = ly + i * 8;
    t[c][lx] = src[(size_t)(c0 + c) * 512 + n0 + lx];
  }
  __syncthreads();
#pragma unroll
  for (int i = 0; i < 4; ++i) {
    int n = ly + i * 8;
    dst[(size_t)(n0 + n) * 512 + c0 + lx] = cvt_bf16(t[lx][n]);
  }
}

__global__ void k_bias_concat(const float* __restrict__ bq, const float* __restrict__ bk,
                              float* __restrict__ bqk) {
  int i = blockIdx.x * 256 + threadIdx.x;
  if (i < 512) bqk[i] = bq[i];
  else if (i < 1024) bqk[i] = bk[i - 512];
}

// ---------------- GroupNorm stats ----------------
__global__ __launch_bounds__(256) void k_gn_stats(const float* __restrict__ x,
                                                  float* __restrict__ stats) {
  int bg = blockIdx.x;
  const float* p = x + (size_t)bg * 65536;
  float s = 0.f, ss = 0.f;
#pragma unroll 4
  for (int i = 0; i < 64; ++i) {
    float4 v = *(const float4*)(p + i * 1024 + threadIdx.x * 4);
    s += v.x + v.y + v.z + v.w;
    ss += v.x * v.x + v.y * v.y + v.z * v.z + v.w * v.w;
  }
#pragma unroll
  for (int m = 1; m < 64; m <<= 1) {
    s += __shfl_xor(s, m, 64);
    ss += __shfl_xor(ss, m, 64);
  }
  __shared__ float red[8];
  int w = threadIdx.x >> 6;
  if ((threadIdx.x & 63) == 0) { red[w * 2] = s; red[w * 2 + 1] = ss; }
  __syncthreads();
  if (threadIdx.x == 0) {
    float S1 = red[0] + red[2] + red[4] + red[6];
    float S2 = red[1] + red[3] + red[5] + red[7];
    float mean = S1 * (1.f / 65536.f);
    float var = S2 * (1.f / 65536.f) - mean * mean;
    stats[bg * 2] = mean;
    stats[bg * 2 + 1] = rsqrtf(var + 1e-6f);
  }
}

// ---------------- normalize + transpose -> h_t[b*4096+p][c] bf16 ----------------
__global__ __launch_bounds__(256) void k_gn_apply(const float* __restrict__ x,
    const float* __restrict__ stats, const float* __restrict__ gsc,
    const float* __restrict__ gbi, short* __restrict__ h_t) {
  __shared__ float t[64][65];
  int p0 = blockIdx.x * 64, c0 = blockIdx.y * 64, b = blockIdx.z;
  int lp = threadIdx.x & 63, lc = threadIdx.x >> 6;
#pragma unroll
  for (int i = 0; i < 16; ++i) {
    int c = c0 + lc * 16 + i;
    float mean = stats[(b * 32 + (c >> 4)) * 2];
    float rstd = stats[(b * 32 + (c >> 4)) * 2 + 1];
    float v = x[((size_t)b * 512 + c) * 4096 + p0 + lp];
    t[lc * 16 + i][lp] = (v - mean) * rstd * gsc[c] + gbi[c];
  }
  __syncthreads();
  int pl = threadIdx.x >> 2;
  int cs = (threadIdx.x & 3) * 16;
  short8 v8a, v8b;
#pragma unroll
  for (int j = 0; j < 8; ++j) v8a[j] = cvt_bf16(t[cs + j][pl]);
#pragma unroll
  for (int j = 0; j < 8; ++j) v8b[j] = cvt_bf16(t[cs + 8 + j][pl]);
  size_t o = ((size_t)(b * 4096 + p0 + pl)) * 512 + c0 + cs;
  *(short8*)(h_t + o) = v8a;
  *(short8*)(h_t + o + 8) = v8b;
}

// ---------------- GEMM: A[M][512] x B[N][512] (K-major bf16) -> C[M][N] ----------------
template <int BIAS_M, int FINAL>
__global__ __launch_bounds__(256) void k_gemm(const short* __restrict__ A,
    const short* __restrict__ Bm, const float* __restrict__ bias,
    short* __restrict__ Cb, float* __restrict__ Cf, const float* __restrict__ resid,
    int ldc) {
  __shared__ __align__(16) short a_lds[128 * 32];
  __shared__ __align__(16) short b_lds[128 * 32];
  int m0 = blockIdx.x * 128, n0 = blockIdx.y * 128;
  int lane = threadIdx.x & 63, wid = threadIdx.x >> 6;
  int h16 = lane >> 4, l16 = lane & 15;
  int wr = wid >> 1, wc = wid & 1;

  f32x4 acc[4][4];
#pragma unroll
  for (int mi = 0; mi < 4; ++mi)
#pragma unroll
    for (int ni = 0; ni < 4; ++ni) acc[mi][ni] = (f32x4){0.f, 0.f, 0.f, 0.f};

  for (int kk = 0; kk < 16; ++kk) {
#pragma unroll
    for (int i = 0; i < 4; ++i) {
      int idx = wid * 4 + i;
      int mat = idx >> 3, h = (idx >> 1) & 3, rh = idx & 1;
      const short* src = (mat ? Bm : A) +
          ((size_t)((mat ? n0 : m0) + rh * 64 + lane)) * 512 + kk * 32 + h * 8;
      short* dst = (mat ? b_lds : a_lds) + (h * 128 + rh * 64) * 8;
      gload_lds16(src, dst);
    }
    asm volatile("s_waitcnt vmcnt(0)" ::: "memory");
    __syncthreads();
    short8 af[4], bf[4];
#pragma unroll
    for (int mi = 0; mi < 4; ++mi)
      af[mi] = *(const short8*)(a_lds + (h16 * 128 + wr * 64 + mi * 16 + l16) * 8);
#pragma unroll
    for (int ni = 0; ni < 4; ++ni)
      bf[ni] = *(const short8*)(b_lds + (h16 * 128 + wc * 64 + ni * 16 + l16) * 8);
#pragma unroll
    for (int mi = 0; mi < 4; ++mi)
#pragma unroll
      for (int ni = 0; ni < 4; ++ni)
        acc[mi][ni] = __builtin_amdgcn_mfma_f32_16x16x32_bf16(af[mi], bf[ni], acc[mi][ni], 0, 0, 0);
    __syncthreads();
  }

#pragma unroll
  for (int mi = 0; mi < 4; ++mi)
#pragma unroll
    for (int ni = 0; ni < 4; ++ni)
#pragma unroll
      for (int r = 0; r < 4; ++r) {
        int row = m0 + wr * 64 + mi * 16 + 4 * h16 + r;
        int col = n0 + wc * 64 + ni * 16 + l16;
        float v = acc[mi][ni][r] + (BIAS_M ? bias[row] : bias[col]);
        if (FINAL) {
          size_t oidx = ((size_t)((col >> 12) * 512 + row)) * 4096 + (col & 4095);
          Cf[oidx] = v + resid[oidx];
        } else {
          Cb[(size_t)row * ldc + col] = cvt_bf16(v);
        }
      }
}

// ---------------- flash attention v8: wave-level software pipeline (T15) ----------------
// QBLK=128, KVBLK=32, kv-split=2, 8 waves = 4 qg x 2 dh, 32x32x16 MFMA.
// Iter t: QK(t) MFMA overlaps softmax(t-1) VALU; then exchange S(t); then PV(t-1).
// K single-buffer staged post-BarA (v3-proven); V double-buffered staged strictly
// post-BarB into the buffer whose PV reads were just drained. stC carried in regs.
__global__ __launch_bounds__(512, 2) void k_flash8(const short* __restrict__ qk,
    const short* __restrict__ v_t, short* __restrict__ oa, short* __restrict__ ob,
    float* __restrict__ ml) {
  __shared__ __align__(16) short k_lds[32 * 512];      // [ks(32)][lane(64)][j(8)] 32KB
  __shared__ __align__(16) short v_lds[2 * 32 * 512];  // dbuf                     64KB
  __shared__ __align__(16) float s_lds[8 * 1024];      // [wid][q4][lane][4]       32KB

  const int tid = threadIdx.x;
  const int lane = tid & 63, wid = tid >> 6;
  const int qg = wid >> 1, dh = wid & 1;
  const int l31 = lane & 31, h = lane >> 5;
  const int bx = blockIdx.x;
  const int combo = bx & 7, qt = bx >> 3;
  const int b = combo >> 1, s = combo & 1;
  const float K2 = 0.06376649f;  // log2(e)/sqrt(512)

  short8 qf[16];
  {
    const short* qbase = qk + ((size_t)(b * 4096 + qt * 128 + qg * 32 + l31)) * 1024
                         + dh * 256 + h * 8;
#pragma unroll
    for (int s_ = 0; s_ < 16; ++s_) qf[s_] = *(const short8*)(qbase + s_ * 16);
  }

  const size_t kvrow0 = (size_t)(b * 4096 + s * 2048);

#define STAGE_K8(T)                                                                   \
  {                                                                                   \
    int t_ = (T);                                                                     \
    _Pragma("unroll") for (int i = 0; i < 4; ++i) {                                   \
      int ks = wid * 4 + i;                                                           \
      gload_lds16(qk + (kvrow0 + t_ * 32 + l31) * 1024 + 512 + ks * 16 + h * 8,       \
                  k_lds + ks * 512);                                                  \
    }                                                                                 \
  }
#define STAGE_V8(T, DST)                                                              \
  {                                                                                   \
    int t_ = (T);                                                                     \
    short* d_ = (DST);                                                                \
    _Pragma("unroll") for (int i = 0; i < 4; ++i) {                                   \
      int si = wid * 4 + i;                                                           \
      int ks = si >> 4, d0 = si & 15;                                                 \
      gload_lds16(v_t + (size_t)(d0 * 32 + l31) * 16384                               \
                      + (kvrow0 + t_ * 32 + ks * 16 + h * 8),                         \
                  d_ + si * 512);                                                     \
    }                                                                                 \
  }
// QK^T partial: S^T [32 kv][32 q] over dh's 256 d, from k_lds
#define QK8(ST)                                                                       \
  _Pragma("unroll") for (int s_ = 0; s_ < 16; ++s_) {                                 \
    short8 kf = *(const short8*)(k_lds + ((dh * 16 + s_) * 64 + lane) * 8);           \
    ST = __builtin_amdgcn_mfma_f32_32x32x16_bf16(kf, qf[s_], ST, 0, 0, 0);            \
  }
// softmax on combined STC (prev tile) -> P packed into PA; updates m_run,l_run,acc
#define SOFTMAX8(STC, PA)                                                             \
  {                                                                                   \
    float u0 = fmaxf(STC[0], STC[1]),  u1 = fmaxf(STC[2], STC[3]);                    \
    float u2 = fmaxf(STC[4], STC[5]),  u3 = fmaxf(STC[6], STC[7]);                    \
    float u4 = fmaxf(STC[8], STC[9]),  u5 = fmaxf(STC[10], STC[11]);                  \
    float u6 = fmaxf(STC[12], STC[13]), u7 = fmaxf(STC[14], STC[15]);                 \
    float mt = fmaxf(fmaxf(fmaxf(u0, u1), fmaxf(u2, u3)),                             \
                     fmaxf(fmaxf(u4, u5), fmaxf(u6, u7)));                            \
    mt = fmaxf(mt, __shfl_xor(mt, 32));                                               \
    if (__any(mt > m_run + 45.0f)) {                                                  \
      float mnew = fmaxf(m_run, mt);                                                  \
      float rs = exp2f((m_run - mnew) * K2);                                          \
      m_run = mnew;                                                                   \
      l_run *= rs;                                                                    \
      _Pragma("unroll") for (int r = 0; r < 16; ++r) {                                \
        int rowq = (r & 3) + 8 * (r >> 2) + 4 * h;                                    \
        float rr = __shfl(rs, rowq);                                                  \
        _Pragma("unroll") for (int tl = 0; tl < 8; ++tl) acc[tl][r] *= rr;            \
      }                                                                               \
    }                                                                                 \
    float ls = 0.f;                                                                   \
    _Pragma("unroll") for (int r = 0; r < 16; ++r) {                                  \
      STC[r] = exp2f((STC[r] - m_run) * K2); ls += STC[r];                            \
    }                                                                                 \
    ls += __shfl_xor(ls, 32);                                                         \
    l_run += ls;                                                                      \
    _Pragma("unroll") for (int ks = 0; ks < 2; ++ks) {                                \
      unsigned int a0, a1, a2, a3;                                                    \
      int bse = ks * 8;                                                               \
      asm("v_cvt_pk_bf16_f32 %0, %1, %2" : "=v"(a0) : "v"(STC[bse+0]), "v"(STC[bse+1])); \
      asm("v_cvt_pk_bf16_f32 %0, %1, %2" : "=v"(a1) : "v"(STC[bse+2]), "v"(STC[bse+3])); \
      asm("v_cvt_pk_bf16_f32 %0, %1, %2" : "=v"(a2) : "v"(STC[bse+4]), "v"(STC[bse+5])); \
      asm("v_cvt_pk_bf16_f32 %0, %1, %2" : "=v"(a3) : "v"(STC[bse+6]), "v"(STC[bse+7])); \
      asm("v_permlane32_swap_b32 %0, %1" : "+v"(a0), "+v"(a2));                       \
      asm("v_permlane32_swap_b32 %0, %1" : "+v"(a1), "+v"(a3));                       \
      uint4v w; w[0] = a0; w[1] = a1; w[2] = a2; w[3] = a3;                           \
      PA[ks] = __builtin_bit_cast(short8, w);                                         \
    }                                                                                 \
  }
#define SWRITE8(ST)                                                                   \
  {                                                                                   \
    float* sp = s_lds + wid * 1024 + lane * 4;                                        \
    _Pragma("unroll") for (int q4 = 0; q4 < 4; ++q4) {                                \
      f32x4 v = {ST[q4*4+0], ST[q4*4+1], ST[q4*4+2], ST[q4*4+3]};                     \
      *(f32x4*)(sp + q4 * 256) = v;                                                   \
    }                                                                                 \
  }
#define SCOMBINE8(ST, STC)                                                            \
  {                                                                                   \
    const float* sp = s_lds + (wid ^ 1) * 1024 + lane * 4;                            \
    _Pragma("unroll") for (int q4 = 0; q4 < 4; ++q4) {                                \
      f32x4 v = *(const f32x4*)(sp + q4 * 256);                                       \
      STC[q4*4+0] = ST[q4*4+0] + v[0]; STC[q4*4+1] = ST[q4*4+1] + v[1];               \
      STC[q4*4+2] = ST[q4*4+2] + v[2]; STC[q4*4+3] = ST[q4*4+3] + v[3];               \
    }                                                                                 \
  }
#define PV8(PA, VSRC)                                                                 \
  _Pragma("unroll") for (int ks = 0; ks < 2; ++ks)                                    \
    _Pragma("unroll") for (int tl = 0; tl < 8; ++tl) {                                \
      short8 vb = *(const short8*)((VSRC) + ((ks * 16 + dh * 8 + tl) * 64 + lane) * 8); \
      acc[tl] = __builtin_amdgcn_mfma_f32_32x32x16_bf16(PA[ks], vb, acc[tl], 0, 0, 0); \
    }

  float m_run = -3.0e38f, l_run = 0.f;
  f32x16 acc[8];
#pragma unroll
  for (int tl = 0; tl < 8; ++tl)
#pragma unroll
    for (int r = 0; r < 16; ++r) acc[tl][r] = 0.f;

  // ---- prologue + peeled iter 0
  STAGE_K8(0);
  STAGE_V8(0, v_lds);
  asm volatile("s_waitcnt vmcnt(0)" ::: "memory");
  __builtin_amdgcn_s_barrier();
  __builtin_amdgcn_sched_barrier(0);

  f32x16 stC;
  {
    f32x16 st;
#pragma unroll
    for (int r = 0; r < 16; ++r) st[r] = 0.f;
    __builtin_amdgcn_s_setprio(1);
    QK8(st);
    __builtin_amdgcn_s_setprio(0);
    SWRITE8(st);
    asm volatile("s_waitcnt lgkmcnt(0)" ::: "memory");
    __builtin_amdgcn_s_barrier();                    // BarA(0)
    __builtin_amdgcn_sched_barrier(0);
    STAGE_K8(1);
    SCOMBINE8(st, stC);
    asm volatile("s_waitcnt vmcnt(0) lgkmcnt(0)" ::: "memory");  // K(1) landed, reads done
    __builtin_amdgcn_s_barrier();                    // BarB(0)
    __builtin_amdgcn_sched_barrier(0);
    STAGE_V8(1, v_lds + 32 * 512);
  }

  // ---- steady state t = 1..63
  for (int t = 1; t < 64; ++t) {
    const int tn = (t + 1 < 64) ? t + 1 : 63;
    const short* vprev = v_lds + ((t - 1) & 1) * (32 * 512);
    short* vnext = v_lds + ((t + 1) & 1) * (32 * 512);
    // 1. QK(t) — fills matrix pipe
    f32x16 st;
#pragma unroll
    for (int r = 0; r < 16; ++r) st[r] = 0.f;
    __builtin_amdgcn_s_setprio(1);
    QK8(st);
    __builtin_amdgcn_s_setprio(0);
    // 2. softmax(t-1) — VALU, overlaps QK pipe time
    short8 pa[2];
    SOFTMAX8(stC, pa);
    // 3. publish S(t)
    SWRITE8(st);
    asm volatile("s_waitcnt lgkmcnt(0)" ::: "memory");
    __builtin_amdgcn_s_barrier();                    // BarA(t)
    __builtin_amdgcn_sched_barrier(0);
    // 5. stage K(t+1) (k reads drained at BarA)
    if (t < 63) STAGE_K8(tn);
    // 6. combine S(t) for next iter
    SCOMBINE8(st, stC);
    // 7. PV(t-1)
    __builtin_amdgcn_s_setprio(1);
    PV8(pa, vprev);
    __builtin_amdgcn_s_setprio(0);
    // 8. K(t+1) landed; combine + PV LDS reads drained
    asm volatile("s_waitcnt vmcnt(0) lgkmcnt(0)" ::: "memory");
    __builtin_amdgcn_s_barrier();                    // BarB(t)
    __builtin_amdgcn_sched_barrier(0);
    // 9. stage V(t+1) into the buffer PV(t-1) just finished reading
    if (t < 63) STAGE_V8(tn, vnext);
  }

  // ---- epilogue: softmax(63) + PV(63)
  {
    short8 pa[2];
    SOFTMAX8(stC, pa);
    PV8(pa, v_lds + (63 & 1) * (32 * 512));
  }

  float linv = 1.0f / l_run;
  short* obuf = (s == 0) ? oa : ob;
#pragma unroll
  for (int r = 0; r < 16; ++r) {
    int rowq = (r & 3) + 8 * (r >> 2) + 4 * h;
    float li = __shfl(linv, rowq);
    size_t grow = ((size_t)(b * 4096 + qt * 128 + qg * 32 + rowq)) * 512;
#pragma unroll
    for (int tl = 0; tl < 8; ++tl)
      obuf[grow + dh * 256 + tl * 32 + l31] = cvt_bf16(acc[tl][r] * li);
  }
  if (dh == 0 && lane < 32) {
    int gq = b * 4096 + qt * 128 + qg * 32 + lane;
    ml[((size_t)s * 16384 + gq) * 2 + 0] = m_run;
    ml[((size_t)s * 16384 + gq) * 2 + 1] = l_run;
  }
#undef STAGE_K8
#undef STAGE_V8
#undef QK8
#undef SOFTMAX8
#undef SWRITE8
#undef SCOMBINE8
#undef PV8
}

// ---------------- combine the two kv-split partials (in place over Ob) ----------------
__global__ __launch_bounds__(256) void k_combine(const short* __restrict__ oa,
    const float* __restrict__ ml, short* __restrict__ ob_out) {
  int gq = blockIdx.x * 4 + (threadIdx.x >> 6);
  int d0 = (threadIdx.x & 63) * 8;
  const float K2 = 0.06376649f;
  float ma = ml[(size_t)gq * 2 + 0], la = ml[(size_t)gq * 2 + 1];
  float mb = ml[((size_t)16384 + gq) * 2 + 0], lb = ml[((size_t)16384 + gq) * 2 + 1];
  float m = fmaxf(ma, mb);
  float wa = exp2f((ma - m) * K2) * la;
  float wb = exp2f((mb - m) * K2) * lb;
  float denom = wa + wb;
  float fa, fb;
  if (isfinite(denom) && denom > 0.f) {
    float inv = 1.f / denom;
    fa = wa * inv; fb = wb * inv;
  } else {
    fa = (ma >= mb) ? 1.f : 0.f;
    fb = 1.f - fa;
  }
  short8 a = *(const short8*)(oa + (size_t)gq * 512 + d0);
  short8 bv = *(const short8*)(ob_out + (size_t)gq * 512 + d0);
  short8 o;
#pragma unroll
  for (int j = 0; j < 8; ++j)
    o[j] = cvt_bf16(fa * bf16_to_f32(a[j]) + fb * bf16_to_f32(bv[j]));
  *(short8*)(ob_out + (size_t)gq * 512 + d0) = o;
}

extern "C" void kernel_launch(void* const* d_in, const int* in_sizes, int n_in,
                              void* d_out, int out_size, void* d_ws, size_t ws_size,
                              hipStream_t stream) {
  const float* x   = (const float*)d_in[0];
  const float* gsc = (const float*)d_in[1];
  const float* gbi = (const float*)d_in[2];
  const float* wq  = (const float*)d_in[3];
  const float* bq  = (const float*)d_in[4];
  const float* wk  = (const float*)d_in[5];
  const float* bk  = (const float*)d_in[6];
  const float* wv  = (const float*)d_in[7];
  const float* bv  = (const float*)d_in[8];
  const float* wo  = (const float*)d_in[9];
  const float* bo  = (const float*)d_in[10];
  float* out = (float*)d_out;

  char* ws = (char*)d_ws;
  float* stats = (float*)ws;                             // 1 KB
  float* bqk   = (float*)(ws + 4096);                    // 4 KB
  short* wqk_t = (short*)(ws + 16384);                   // 1 MB  [1024][512]
  short* wv_t  = (short*)(ws + 16384 + (1u << 20));      // 0.5 MB
  short* wo_t  = (short*)(ws + 16384 + (1u << 20) + (1u << 19));
  char*  big   = ws + 16384 + (1u << 21);
  short* h_t   = (short*)big;                            // 16 MB [16384][512]; reused as Oa
  short* qkb   = (short*)(big + (16ll << 20));           // 32 MB [16384][1024]
  short* v_t   = (short*)(big + (48ll << 20));           // 16 MB [512][16384]
  short* o_at  = (short*)(big + (64ll << 20));           // 16 MB [16384][512]; Ob then final
  float* mlbuf = (float*)(big + (80ll << 20));           // 256 KB [2][16384][2]

  dim3 b256(256);
  k_transpose_w<<<dim3(16, 16), b256, 0, stream>>>(wq, wqk_t);
  k_transpose_w<<<dim3(16, 16), b256, 0, stream>>>(wk, wqk_t + 512 * 512);
  k_transpose_w<<<dim3(16, 16), b256, 0, stream>>>(wv, wv_t);
  k_transpose_w<<<dim3(16, 16), b256, 0, stream>>>(wo, wo_t);
  k_bias_concat<<<4, 256, 0, stream>>>(bq, bk, bqk);
  k_gn_stats<<<128, b256, 0, stream>>>(x, stats);
  k_gn_apply<<<dim3(64, 8, 4), b256, 0, stream>>>(x, stats, gsc, gbi, h_t);
  // Q|K projection -> qkb[16384][1024]
  k_gemm<0, 0><<<dim3(128, 8), b256, 0, stream>>>(h_t, wqk_t, bqk, qkb, nullptr, nullptr, 1024);
  // V projection transposed -> v_t[512][16384]
  k_gemm<1, 0><<<dim3(4, 128), b256, 0, stream>>>(wv_t, h_t, bv, v_t, nullptr, nullptr, 16384);
  // flash attention (h_t now dead -> Oa; o_at holds Ob)
  k_flash8<<<dim3(256), dim3(512), 0, stream>>>(qkb, v_t, h_t, o_at, mlbuf);
  k_combine<<<dim3(4096), b256, 0, stream>>>(h_t, mlbuf, o_at);
  // output projection transposed + bias + residual -> fp32 out
  k_gemm<1, 1><<<dim3(4, 128), b256, 0, stream>>>(wo_t, o_at, bo, nullptr, out, x, 0);
}